// Round 1
// baseline (206.809 us; speedup 1.0000x reference)
//
#include <hip/hip_runtime.h>

#define BB 16
#define CC 256
#define NN 4096
#define CN (CC*NN)
#define GG 8
#define EPSF 1e-8f

// ---------------- transpose conv_w -> wT[c][d] (so conv reads are wave-uniform) -------------
__global__ __launch_bounds__(256) void k_wt(const float* __restrict__ conv_w,
                                            float* __restrict__ wT) {
  int o = blockIdx.x * 256 + threadIdx.x;  // 16384
  int d = o >> 8, c = o & 255;
  wT[c * 64 + d] = conv_w[d * 256 + c];
}

// ---------------- conv(1x1)+relu+pool partials + x passthrough ------------------------------
// grid: 16 b x 16 n-chunks(256). thread = one spatial n, acc[64] over d, loop c.
// wT[c][d], conv_b uniform -> scalar loads. pooledpart[b][sub(64)][d], sub = nt*4+wave.
__global__ __launch_bounds__(256) void k_conv(const float* __restrict__ x,
                                              const float* __restrict__ wT,
                                              const float* __restrict__ conv_b,
                                              float* __restrict__ pooledpart,
                                              float* __restrict__ xout) {
  const int b = blockIdx.x >> 4;
  const int nt = blockIdx.x & 15;
  const int t = threadIdx.x;
  const size_t base = (size_t)b * CN + nt * 256 + t;
  const float* xp = x + base;
  float* xo = xout + base;
  float acc[64];
#pragma unroll
  for (int d = 0; d < 64; ++d) acc[d] = 0.f;
#pragma unroll 4
  for (int c = 0; c < 256; ++c) {
    float xv = xp[(size_t)c * NN];
    xo[(size_t)c * NN] = xv;
    const float* wc = wT + c * 64;  // uniform address -> s_load
#pragma unroll
    for (int d = 0; d < 64; ++d) acc[d] = fmaf(wc[d], xv, acc[d]);
  }
  const int lane = t & 63, wv = t >> 6;
#pragma unroll
  for (int d = 0; d < 64; ++d) {
    float h = fmaxf(acc[d] + conv_b[d], 0.f);
#pragma unroll
    for (int off = 1; off < 64; off <<= 1) h += __shfl_xor(h, off, 64);
    acc[d] = h;
  }
  if (lane == 0) {
    float* pp = pooledpart + ((size_t)b * 64 + nt * 4 + wv) * 64;
#pragma unroll
    for (int d = 0; d < 64; ++d) pp[d] = acc[d];
  }
}

// ---------------- x row norms ---------------------------------------------------------------
__global__ __launch_bounds__(256) void k_xnorm(const float* __restrict__ x,
                                               float* __restrict__ xnorm) {
  const int bc = blockIdx.x;  // b*256+c
  const float4* xr = (const float4*)(x + (size_t)bc * NN);
  const int t = threadIdx.x;
  float s = 0.f;
#pragma unroll
  for (int j = 0; j < 4; ++j) {
    float4 v = xr[t + j * 256];
    s += v.x * v.x + v.y * v.y + v.z * v.z + v.w * v.w;
  }
#pragma unroll
  for (int off = 1; off < 64; off <<= 1) s += __shfl_xor(s, off, 64);
  __shared__ float red[4];
  if ((t & 63) == 0) red[t >> 6] = s;
  __syncthreads();
  if (t == 0) {
    float nrm = sqrtf(red[0] + red[1] + red[2] + red[3]);
    xnorm[bc] = fmaxf(nrm, EPSF);
  }
}

// ---------------- pooled = mean of partials -------------------------------------------------
__global__ __launch_bounds__(64) void k_pooled(const float* __restrict__ pooledpart,
                                               float* __restrict__ pooled) {
  const int b = blockIdx.x, d = threadIdx.x;
  float s = 0.f;
#pragma unroll 8
  for (int k = 0; k < 64; ++k) s += pooledpart[((size_t)b * 64 + k) * 64 + d];
  pooled[b * 64 + d] = s * (1.f / 4096.f);
}

// ---------------- logits = pooled @ lin_w.T + lin_b + log(ga+eps) ---------------------------
__global__ __launch_bounds__(256) void k_logits(const float* __restrict__ pooled,
                                                const float* __restrict__ lin_w,
                                                const float* __restrict__ lin_b,
                                                const float* __restrict__ ga,
                                                float* __restrict__ logits) {
  const int b = blockIdx.x, c = threadIdx.x;
  const float* pb = pooled + b * 64;  // uniform -> s_load
  float out[8];
#pragma unroll
  for (int g = 0; g < 8; ++g) {
    const float4* wr = (const float4*)(lin_w + ((size_t)c * 8 + g) * 64);
    float s = 0.f;
#pragma unroll
    for (int k4 = 0; k4 < 16; ++k4) {
      float4 wv = wr[k4];
      s += wv.x * pb[k4 * 4] + wv.y * pb[k4 * 4 + 1] + wv.z * pb[k4 * 4 + 2] +
           wv.w * pb[k4 * 4 + 3];
    }
    out[g] = s + lin_b[c * 8 + g] + logf(ga[((size_t)b * 256 + c) * 8 + g] + EPSF);
  }
  float* lp = logits + ((size_t)b * 256 + c) * 8;
  *(float4*)lp = make_float4(out[0], out[1], out[2], out[3]);
  *(float4*)(lp + 4) = make_float4(out[4], out[5], out[6], out[7]);
}

// ---------------- w = softmax(logits) over g ------------------------------------------------
__global__ __launch_bounds__(256) void k_w(const float* __restrict__ logits,
                                           float* __restrict__ wg) {
  const size_t i = (size_t)blockIdx.x * 256 + threadIdx.x;  // b*256+c
  const float4* lp = (const float4*)(logits + i * 8);
  float4 a = lp[0], b4 = lp[1];
  float v[8] = {a.x, a.y, a.z, a.w, b4.x, b4.y, b4.z, b4.w};
  float m = v[0];
#pragma unroll
  for (int g = 1; g < 8; ++g) m = fmaxf(m, v[g]);
  float sum = 0.f;
#pragma unroll
  for (int g = 0; g < 8; ++g) { v[g] = __expf(v[g] - m); sum += v[g]; }
  float r = 1.f / sum;
  float4* op = (float4*)(wg + i * 8);
  op[0] = make_float4(v[0] * r, v[1] * r, v[2] * r, v[3] * r);
  op[1] = make_float4(v[4] * r, v[5] * r, v[6] * r, v[7] * r);
}

// ---------------- s[b][g][n] = sum_c w[b][c][g] * x[b][c][n]  (+ s^2 partials) --------------
// grid: 16 b x 32 n-chunks(128). thread: 2 n (float2), 8 g; waves split c 4-ways.
__global__ __launch_bounds__(256) void k_s(const float* __restrict__ x,
                                           const float* __restrict__ wg,
                                           float* __restrict__ s,
                                           float* __restrict__ spart2) {
  const int b = blockIdx.x >> 5, nt = blockIdx.x & 31;
  const int t = threadIdx.x;
  const int nl = t & 63;
  const int cq = __builtin_amdgcn_readfirstlane(t >> 6);
  const int n0 = nt * 128;
  float ax[8], ay[8];
#pragma unroll
  for (int g = 0; g < 8; ++g) { ax[g] = 0.f; ay[g] = 0.f; }
  const float* wb = wg + (size_t)b * 2048 + cq * 512;  // uniform -> s_load
  const float* xb = x + (size_t)b * CN + (size_t)(cq * 64) * NN + n0 + nl * 2;
#pragma unroll 4
  for (int cc = 0; cc < 64; ++cc) {
    const float2 xv = *(const float2*)(xb + (size_t)cc * NN);
    const float* wc = wb + cc * 8;
#pragma unroll
    for (int g = 0; g < 8; ++g) {
      ax[g] = fmaf(wc[g], xv.x, ax[g]);
      ay[g] = fmaf(wc[g], xv.y, ay[g]);
    }
  }
  __shared__ float part[4][8][128];
#pragma unroll
  for (int g = 0; g < 8; ++g) {
    part[cq][g][nl * 2] = ax[g];
    part[cq][g][nl * 2 + 1] = ay[g];
  }
  __syncthreads();
  float* sb = s + (size_t)b * 8 * NN + n0;
#pragma unroll
  for (int k = 0; k < 2; ++k) {
    int f2 = k * 256 + t;
    int g = f2 >> 6, np = f2 & 63;
    float vx = part[0][g][np * 2] + part[1][g][np * 2] + part[2][g][np * 2] + part[3][g][np * 2];
    float vy = part[0][g][np * 2 + 1] + part[1][g][np * 2 + 1] + part[2][g][np * 2 + 1] +
               part[3][g][np * 2 + 1];
    *(float2*)(sb + (size_t)g * NN + np * 2) = make_float2(vx, vy);
    float s2 = vx * vx + vy * vy;
#pragma unroll
    for (int off = 1; off < 64; off <<= 1) s2 += __shfl_xor(s2, off, 64);
    if ((t & 63) == 0) spart2[((size_t)b * 32 + nt) * 8 + g] = s2;
  }
}

// ---------------- sim partials: simpart[b][nt][c][g] = sum_{n in chunk} x*s ------------------
// grid: 16 b x 16 n-chunks(256) x 4 c-quarters(64). LDS-staged x tile, 8c x 8g per thread.
__global__ __launch_bounds__(256) void k_sim(const float* __restrict__ x,
                                             const float* __restrict__ s,
                                             float* __restrict__ simpart) {
  const int blk = blockIdx.x;
  const int cq = blk & 3, nt = (blk >> 2) & 15, b = blk >> 6;
  const int t = threadIdx.x;
  const int n0 = nt * 256, c0 = cq * 64;
  __shared__ float xs[64][260];    // 260-f32 row stride: 16B-aligned, spreads banks
  __shared__ float slbuf[8][260];  // s tile; reused as reduce pool after barrier
  {
    const float* xb = x + (size_t)b * CN + (size_t)c0 * NN + n0;
#pragma unroll
    for (int k = 0; k < 16; ++k) {
      int f = k * 256 + t;
      int r = f >> 6, j = f & 63;
      float4 v = *(const float4*)(xb + (size_t)r * NN + j * 4);
      *(float4*)&xs[r][j * 4] = v;
    }
    const float* sb = s + (size_t)b * 8 * NN + n0;
#pragma unroll
    for (int k = 0; k < 2; ++k) {
      int f = k * 256 + t;
      int g = f >> 6, j = f & 63;
      float4 v = *(const float4*)(sb + (size_t)g * NN + j * 4);
      *(float4*)&slbuf[g][j * 4] = v;
    }
  }
  __syncthreads();
  const int co = t & 7;
  const int nq = t >> 3;  // 0..31, 8 n each
  float acc[8][8];
#pragma unroll
  for (int k = 0; k < 8; ++k)
#pragma unroll
    for (int g = 0; g < 8; ++g) acc[k][g] = 0.f;
#pragma unroll
  for (int jv = 0; jv < 2; ++jv) {
    const int nb = nq * 8 + jv * 4;
    float4 sv[8];
#pragma unroll
    for (int g = 0; g < 8; ++g) sv[g] = *(const float4*)&slbuf[g][nb];
#pragma unroll
    for (int k = 0; k < 8; ++k) {
      float4 xv = *(const float4*)&xs[co + 8 * k][nb];
#pragma unroll
      for (int g = 0; g < 8; ++g) {
        acc[k][g] = fmaf(xv.x, sv[g].x, acc[k][g]);
        acc[k][g] = fmaf(xv.y, sv[g].y, acc[k][g]);
        acc[k][g] = fmaf(xv.z, sv[g].z, acc[k][g]);
        acc[k][g] = fmaf(xv.w, sv[g].w, acc[k][g]);
      }
    }
  }
  // sum the 8 nq-subgroups within each wave -> per-wave 64-n partial
#pragma unroll
  for (int k = 0; k < 8; ++k)
#pragma unroll
    for (int g = 0; g < 8; ++g) {
      float v = acc[k][g];
      v += __shfl_xor(v, 8, 64);
      v += __shfl_xor(v, 16, 64);
      v += __shfl_xor(v, 32, 64);
      acc[k][g] = v;
    }
  __syncthreads();  // all reads of slbuf done; reuse as pool[4][8][8][8]
  float* pool = &slbuf[0][0];
  const int wv = t >> 6, l = t & 63;
  if ((l >> 3) == 0) {
#pragma unroll
    for (int k = 0; k < 8; ++k) {
      *(float4*)&pool[((wv * 8 + l) * 8 + k) * 8 + 0] =
          make_float4(acc[k][0], acc[k][1], acc[k][2], acc[k][3]);
      *(float4*)&pool[((wv * 8 + l) * 8 + k) * 8 + 4] =
          make_float4(acc[k][4], acc[k][5], acc[k][6], acc[k][7]);
    }
  }
  __syncthreads();
  float2 ov;
  float* po = &ov.x;
#pragma unroll
  for (int j = 0; j < 2; ++j) {
    int o = t * 2 + j;
    int cl = o >> 3, g = o & 7;
    int co2 = cl & 7, k2 = cl >> 3;
    po[j] = pool[((0 * 8 + co2) * 8 + k2) * 8 + g] + pool[((1 * 8 + co2) * 8 + k2) * 8 + g] +
            pool[((2 * 8 + co2) * 8 + k2) * 8 + g] + pool[((3 * 8 + co2) * 8 + k2) * 8 + g];
  }
  *(float2*)(simpart + (((size_t)b * 16 + nt) * 256 + c0) * 8 + t * 2) = ov;
}

// ---------------- logits += sim/(xn*sn); FINAL: softmax -> d_out ----------------------------
template <int FINAL>
__global__ __launch_bounds__(256) void k_upd(const float* __restrict__ simpart,
                                             const float* __restrict__ xnorm,
                                             const float* __restrict__ spart2,
                                             float* __restrict__ logits,
                                             float* __restrict__ outw) {
  const int b = blockIdx.x, t = threadIdx.x, c = t;
  __shared__ float snr[8];
  if (t < 8) {
    float s2 = 0.f;
    for (int k = 0; k < 32; ++k) s2 += spart2[((size_t)b * 32 + k) * 8 + t];
    snr[t] = 1.f / fmaxf(sqrtf(s2), EPSF);
  }
  __syncthreads();
  const float xni = 1.f / xnorm[b * 256 + c];
  float* lp = logits + ((size_t)b * 256 + c) * 8;
  float4 l0 = *(const float4*)lp, l1 = *(const float4*)(lp + 4);
  float lg[8] = {l0.x, l0.y, l0.z, l0.w, l1.x, l1.y, l1.z, l1.w};
  float sim[8] = {0, 0, 0, 0, 0, 0, 0, 0};
#pragma unroll 4
  for (int k = 0; k < 16; ++k) {
    const float4* sp = (const float4*)(simpart + (((size_t)b * 16 + k) * 256 + c) * 8);
    float4 a = sp[0], bb = sp[1];
    sim[0] += a.x; sim[1] += a.y; sim[2] += a.z; sim[3] += a.w;
    sim[4] += bb.x; sim[5] += bb.y; sim[6] += bb.z; sim[7] += bb.w;
  }
#pragma unroll
  for (int g = 0; g < 8; ++g) lg[g] += sim[g] * xni * snr[g];
  if (!FINAL) {
    *(float4*)lp = make_float4(lg[0], lg[1], lg[2], lg[3]);
    *(float4*)(lp + 4) = make_float4(lg[4], lg[5], lg[6], lg[7]);
  } else {
    float m = lg[0];
#pragma unroll
    for (int g = 1; g < 8; ++g) m = fmaxf(m, lg[g]);
    float sum = 0.f;
#pragma unroll
    for (int g = 0; g < 8; ++g) { lg[g] = __expf(lg[g] - m); sum += lg[g]; }
    float r = 1.f / sum;
    float4* op = (float4*)(outw + ((size_t)b * 256 + c) * 8);
    op[0] = make_float4(lg[0] * r, lg[1] * r, lg[2] * r, lg[3] * r);
    op[1] = make_float4(lg[4] * r, lg[5] * r, lg[6] * r, lg[7] * r);
  }
}

extern "C" void kernel_launch(void* const* d_in, const int* in_sizes, int n_in,
                              void* d_out, int out_size, void* d_ws, size_t ws_size,
                              hipStream_t stream) {
  const float* x = (const float*)d_in[0];
  const float* ga = (const float*)d_in[1];
  const float* conv_w = (const float*)d_in[2];
  const float* conv_b = (const float*)d_in[3];
  const float* lin_w = (const float*)d_in[4];
  const float* lin_b = (const float*)d_in[5];
  float* out = (float*)d_out;
  float* outx = out + 32768;  // x passthrough region

  float* ws = (float*)d_ws;
  float* wT = ws;                   // 16384
  float* pooledpart = ws + 16384;   // 65536
  float* pooled = ws + 81920;       // 1024
  float* logits = ws + 82944;       // 32768
  float* wg = ws + 115712;          // 32768
  float* xnorm = ws + 148480;       // 4096
  float* s = ws + 152576;           // 524288
  float* spart2 = ws + 676864;      // 4096
  float* simpart = ws + 680960;     // 524288  (end: 1205248 floats ~4.6MB)

  k_wt<<<64, 256, 0, stream>>>(conv_w, wT);
  k_conv<<<256, 256, 0, stream>>>(x, wT, conv_b, pooledpart, outx);
  k_xnorm<<<4096, 256, 0, stream>>>(x, xnorm);
  k_pooled<<<16, 64, 0, stream>>>(pooledpart, pooled);
  k_logits<<<16, 256, 0, stream>>>(pooled, lin_w, lin_b, ga, logits);

  // iteration 1
  k_w<<<16, 256, 0, stream>>>(logits, wg);
  k_s<<<512, 256, 0, stream>>>(x, wg, s, spart2);
  k_sim<<<1024, 256, 0, stream>>>(x, s, simpart);
  k_upd<0><<<16, 256, 0, stream>>>(simpart, xnorm, spart2, logits, out);

  // iteration 2 (+ final softmax into d_out)
  k_w<<<16, 256, 0, stream>>>(logits, wg);
  k_s<<<512, 256, 0, stream>>>(x, wg, s, spart2);
  k_sim<<<1024, 256, 0, stream>>>(x, s, simpart);
  k_upd<1><<<16, 256, 0, stream>>>(simpart, xnorm, spart2, logits, out);
}